// Round 9
// baseline (875.361 us; speedup 1.0000x reference)
//
#include <hip/hip_runtime.h>
#include <hip/hip_bf16.h>
#include <hip/hip_fp16.h>

// GCN inference: conv1(128->16)+ReLU -> conv2(16->16) -> linear(16->40) -> log_softmax
// R16 post-mortem: 4-lane agg worked (401->394.6); bucketsort top again (64us,
// WRITE now ideal 50.8MB). Its remaining cost: pass A re-reads ebuf1 (51MB)
// just to count. R17: fold per-node cnt/deg into k_partition as fire-and-forget
// GLOBAL atomics (L2-resident 400KB tables; global f32 unsafeAtomicAdd is the
// intended use -- unlike the R10/R14 __shared__ trap). Fine sort becomes:
// k_bsOffs (bucket scan of cnt -> offs, dinv=rsqrt(deg)) + k_bsB (R15 pass B
// verbatim: LDS-staged scatter, coalesced writeout). Unlike R12's regression,
// counting here costs ZERO extra edge reads. cnt overlays edata after histex
// (dead before bsB writes edata).

#define N_NODES 100000
#define N_EDGES 6400000
#define IN_DIM  128
#define HID     16
#define NCLS    40

#define K_BKT    782         // buckets = col>>7, 128 nodes each (last: 32)
#define BKT_SH   7
#define BKT_NB   128         // nodes per bucket
#define BKT_MASK 127
#define B_PART   1000        // histogram/partition blocks
#define CHUNK    6400        // edges per partition block (fits LDS staging)
#define BS_CAP   9216        // bsB LDS staging capacity (edges)

// ---- tier-1 workspace layout (bytes) ----
#define OFF_CB    0          // int[783] bucket bases
#define OFF_TOT   4096       // int[782] bucket totals
#define OFF_DINV  8192       // float[N]: deg accum (init 1.0), rsqrt in place
#define OFF_OFFS  408192     // int[N+1]
#define OFF_EBUF1 808256     // int2[E] bucket-major edges (dead after bsB)
#define OFF_EDATA 52008256   // int2[E] final CSR (row, w) -- ends 103,208,256
#define OFF_HIST   OFF_EDATA               // int[1000*782] (dead after partition)
#define OFF_HISTEX (OFF_EDATA + 3128000)   // int[1000*782] (dead after partition)
#define OFF_CNT    (OFF_EDATA + 6256000)   // int[N] (init2..bsOffs window)
#define WS_T1_NEED 103600000
// h1/hb (fp16, 3.2MB each) overlay the dead ebuf1 region:
#define OFF_H1    OFF_EBUF1
#define OFF_HB    (OFF_EBUF1 + 3200000)

// ---- tier-2 workspace layout (R5 atomic-CSR path, fp16 h) ----
#define T2_DINV  0
#define T2_CNT   400128
#define T2_OFFS  800256
#define T2_EDATA 1200384
#define T2_H1    52400384
#define T2_HB    58800384
#define T2_BSUM  65200384
#define WS_T2_NEED 65210000

// ---- tier-3 fallback layout ----
#define OFF3_DEG 0
#define OFF3_H1  400128
#define OFF3_HB  6800384

// =================== tier-1: deterministic CSR build ===================

// zero per-node counts; deg = 1.0 (self-loop weight)
__global__ __launch_bounds__(256) void k_init2(int* cnt, float* deg) {
    int i = blockIdx.x * 256 + threadIdx.x;
    if (i < N_NODES) { cnt[i] = 0; deg[i] = 1.0f; }
}

__global__ __launch_bounds__(1024) void k_hist(const int* col, int* histcnt) {
    __shared__ int h[K_BKT];
    int t = threadIdx.x;
    if (t < K_BKT) h[t] = 0;
    __syncthreads();
    int b = blockIdx.x;
    const int4* c4 = (const int4*)(col + b * CHUNK);
    for (int i = t; i < CHUNK / 4; i += 1024) {
        int4 c = c4[i];
        atomicAdd(&h[c.x >> BKT_SH], 1);              // LDS int atomic: fast path
        atomicAdd(&h[c.y >> BKT_SH], 1);
        atomicAdd(&h[c.z >> BKT_SH], 1);
        atomicAdd(&h[c.w >> BKT_SH], 1);
    }
    __syncthreads();
    if (t < K_BKT) histcnt[b * K_BKT + t] = h[t];
}

// one block per bucket k: exclusive-scan histcnt[.][k] over the 1000 blocks
__global__ __launch_bounds__(1024) void k_colscan(const int* histcnt, int* histex, int* tot) {
    __shared__ int s[1024];
    int t = threadIdx.x;
    int k = blockIdx.x;
    int v = (t < B_PART) ? histcnt[t * K_BKT + k] : 0;
    s[t] = v;
    __syncthreads();
    for (int o = 1; o < 1024; o <<= 1) {
        int a = (t >= o) ? s[t - o] : 0;
        __syncthreads();
        s[t] += a;
        __syncthreads();
    }
    if (t < B_PART) histex[t * K_BKT + k] = s[t] - v;  // exclusive
    if (t == 0) tot[k] = s[B_PART - 1];                // inclusive total
}

__global__ __launch_bounds__(1024) void k_basescan(const int* tot, int* cbase) {
    __shared__ int s[1024];
    int t = threadIdx.x;
    int v = (t < K_BKT) ? tot[t] : 0;
    s[t] = v;
    __syncthreads();
    for (int o = 1; o < 1024; o <<= 1) {
        int a = (t >= o) ? s[t - o] : 0;
        __syncthreads();
        s[t] += a;
        __syncthreads();
    }
    if (t < K_BKT) cbase[t] = s[t] - v;               // exclusive
    if (t == 0) cbase[K_BKT] = N_EDGES;
}

// LDS-staged partition + per-node cnt/deg via fire-and-forget global atomics.
// packed = row | (col_local<<17)
__global__ __launch_bounds__(1024) void k_partition(const int* row, const int* col,
                                                    const float* w, const int* histcnt,
                                                    const int* histex, const int* cbase,
                                                    int2* ebuf1, int* cnt, float* deg) {
    __shared__ int2 led[CHUNK];          // 51.2KB staged edges
    __shared__ int  sscan[1024];
    __shared__ int  lbase[K_BKT + 1];
    __shared__ int  gofs[K_BKT];
    __shared__ int  cur[K_BKT];
    int t = threadIdx.x;
    int b = blockIdx.x;
    int v = (t < K_BKT) ? histcnt[b * K_BKT + t] : 0;
    sscan[t] = v;
    __syncthreads();
    for (int o = 1; o < 1024; o <<= 1) {
        int a = (t >= o) ? sscan[t - o] : 0;
        __syncthreads();
        sscan[t] += a;
        __syncthreads();
    }
    if (t < K_BKT) {
        int ex = sscan[t] - v;
        lbase[t] = ex;
        cur[t] = ex;
        gofs[t] = cbase[t] + histex[b * K_BKT + t] - ex;
    }
    if (t == 0) lbase[K_BKT] = CHUNK;
    __syncthreads();
    int end = (b + 1) * CHUNK;
    int e = b * CHUNK + t;
    for (; e + 1024 < end; e += 2048) {
        int c0 = col[e],  c1 = col[e + 1024];
        int r0 = row[e],  r1 = row[e + 1024];
        float w0 = w[e],  w1 = w[e + 1024];
        int p0 = atomicAdd(&cur[c0 >> BKT_SH], 1);
        int p1 = atomicAdd(&cur[c1 >> BKT_SH], 1);
        atomicAdd(&cnt[c0], 1);                       // L2-resident, fire-and-forget
        atomicAdd(&cnt[c1], 1);
        unsafeAtomicAdd(&deg[c0], w0);
        unsafeAtomicAdd(&deg[c1], w1);
        led[p0] = make_int2(r0 | ((c0 & BKT_MASK) << 17), __float_as_int(w0));
        led[p1] = make_int2(r1 | ((c1 & BKT_MASK) << 17), __float_as_int(w1));
    }
    for (; e < end; e += 1024) {
        int c = col[e];
        float wv = w[e];
        int p = atomicAdd(&cur[c >> BKT_SH], 1);
        atomicAdd(&cnt[c], 1);
        unsafeAtomicAdd(&deg[c], wv);
        led[p] = make_int2(row[e] | ((c & BKT_MASK) << 17), __float_as_int(wv));
    }
    __syncthreads();
    for (int i = t; i < CHUNK; i += 1024) {
        int2 ed = led[i];
        int lo = 0, hi = K_BKT;
        while (hi - lo > 1) {
            int mid = (lo + hi) >> 1;
            if (lbase[mid] <= i) lo = mid; else hi = mid;
        }
        ebuf1[gofs[lo] + i] = ed;
    }
}

// per-bucket scan of cnt -> offs; dinv = rsqrt(deg) in place
__global__ __launch_bounds__(BKT_NB) void k_bsOffs(const int* cnt, const int* cbase,
                                                   int* offs, float* dinv) {
    __shared__ int sc[BKT_NB];
    int t = threadIdx.x;
    int k = blockIdx.x;
    int node = k * BKT_NB + t;
    int c = (node < N_NODES) ? cnt[node] : 0;
    sc[t] = c;
    __syncthreads();
    for (int o = 1; o < BKT_NB; o <<= 1) {
        int a = (t >= o) ? sc[t - o] : 0;
        __syncthreads();
        sc[t] += a;
        __syncthreads();
    }
    if (node < N_NODES) {
        offs[node] = cbase[k] + sc[t] - c;
        dinv[node] = rsqrtf(dinv[node]);             // deg (incl. 1.0 self) -> rsqrt
    }
    if (k == 0 && t == 0) offs[N_NODES] = N_EDGES;
}

// pass-B-only fine sort: scatter into LDS at local positions, coalesced writeout.
__global__ __launch_bounds__(1024) void k_bsB(const int2* ebuf1, const int* cbase,
                                              const int* offs, int2* edata) {
    __shared__ int2 led[BS_CAP];         // 73.7KB sorted staging
    __shared__ int  cur[BKT_NB];
    int t = threadIdx.x;
    int k = blockIdx.x;
    int e0 = cbase[k], e1 = cbase[k + 1];
    if (t < BKT_NB) {
        int node = k * BKT_NB + t;
        cur[t] = (node < N_NODES) ? (offs[node] - e0) : 0;   // local position base
    }
    __syncthreads();
    int len = e1 - e0;
    if (len <= BS_CAP) {
        int e = e0 + t;
        for (; e + 3072 < e1; e += 4096) {
            int2 v0 = ebuf1[e];
            int2 v1 = ebuf1[e + 1024];
            int2 v2 = ebuf1[e + 2048];
            int2 v3 = ebuf1[e + 3072];
            int p0 = atomicAdd(&cur[v0.x >> 17], 1);
            int p1 = atomicAdd(&cur[v1.x >> 17], 1);
            int p2 = atomicAdd(&cur[v2.x >> 17], 1);
            int p3 = atomicAdd(&cur[v3.x >> 17], 1);
            led[p0] = make_int2(v0.x & 131071, v0.y);
            led[p1] = make_int2(v1.x & 131071, v1.y);
            led[p2] = make_int2(v2.x & 131071, v2.y);
            led[p3] = make_int2(v3.x & 131071, v3.y);
        }
        for (; e < e1; e += 1024) {
            int2 v = ebuf1[e];
            int p = atomicAdd(&cur[v.x >> 17], 1);
            led[p] = make_int2(v.x & 131071, v.y);
        }
        __syncthreads();
        for (int i = t; i < len; i += 1024)
            edata[e0 + i] = led[i];
    } else {
        // fallback (capacity exceeded; statistically never): direct scatter
        int e = e0 + t;
        for (; e < e1; e += 1024) {
            int2 v = ebuf1[e];
            int p = atomicAdd(&cur[v.x >> 17], 1);
            edata[e0 + p] = make_int2(v.x & 131071, v.y);
        }
    }
}

// =================== shared compute kernels ===================

// h1 = fp16(dinv[node] * (z @ W1))
__global__ __launch_bounds__(256) void k_gemm1(const float* z, const float* W1,
                                               __half* h1, const float* dinv) {
    __shared__ float w1s[IN_DIM * HID];
    __shared__ float zs[64 * 132];
    int tid = threadIdx.x;
    for (int i = tid; i < IN_DIM * HID / 4; i += 256)
        ((float4*)w1s)[i] = ((const float4*)W1)[i];
    int nodeBase = blockIdx.x * 64;
    for (int i = tid; i < 64 * 32; i += 256) {
        int nl = i >> 5, kq = i & 31;
        int node = nodeBase + nl;
        float4 v = (node < N_NODES) ? ((const float4*)z)[node * 32 + kq]
                                    : make_float4(0.f, 0.f, 0.f, 0.f);
        *(float4*)&zs[nl * 132 + kq * 4] = v;
    }
    __syncthreads();
    int nl = tid >> 2;
    int jb = (tid & 3) * 4;
    int node = nodeBase + nl;
    float4 acc = make_float4(0.f, 0.f, 0.f, 0.f);
    for (int k = 0; k < IN_DIM; k++) {
        float s = zs[nl * 132 + k];
        float4 wv = *(const float4*)&w1s[k * HID + jb];
        acc.x += s * wv.x; acc.y += s * wv.y; acc.z += s * wv.z; acc.w += s * wv.w;
    }
    if (node < N_NODES) {
        float dv = dinv ? dinv[node] : 1.0f;
        union { __half2 h2[2]; uint2 u; } pk;
        pk.h2[0] = __floats2half2_rn(acc.x * dv, acc.y * dv);
        pk.h2[1] = __floats2half2_rn(acc.z * dv, acc.w * dv);
        ((uint2*)h1)[node * 4 + (tid & 3)] = pk.u;
    }
}

// f32-output variant for tier-3
__global__ __launch_bounds__(256) void k_gemm1f(const float* z, const float* W1, float* h1,
                                                const float* dinv) {
    __shared__ float w1s[IN_DIM * HID];
    __shared__ float zs[64 * 132];
    int tid = threadIdx.x;
    for (int i = tid; i < IN_DIM * HID / 4; i += 256)
        ((float4*)w1s)[i] = ((const float4*)W1)[i];
    int nodeBase = blockIdx.x * 64;
    for (int i = tid; i < 64 * 32; i += 256) {
        int nl = i >> 5, kq = i & 31;
        int node = nodeBase + nl;
        float4 v = (node < N_NODES) ? ((const float4*)z)[node * 32 + kq]
                                    : make_float4(0.f, 0.f, 0.f, 0.f);
        *(float4*)&zs[nl * 132 + kq * 4] = v;
    }
    __syncthreads();
    int nl = tid >> 2;
    int jb = (tid & 3) * 4;
    int node = nodeBase + nl;
    float4 acc = make_float4(0.f, 0.f, 0.f, 0.f);
    for (int k = 0; k < IN_DIM; k++) {
        float s = zs[nl * 132 + k];
        float4 wv = *(const float4*)&w1s[k * HID + jb];
        acc.x += s * wv.x; acc.y += s * wv.y; acc.z += s * wv.z; acc.w += s * wv.w;
    }
    if (node < N_NODES) {
        float dv = dinv ? dinv[node] : 1.0f;
        acc.x *= dv; acc.y *= dv; acc.z *= dv; acc.w *= dv;
        ((float4*)h1)[node * 4 + (tid & 3)] = acc;
    }
}

// 4-lane/node edge aggregation: each lane gathers uint2 = 4 fp16 features.
__device__ __forceinline__ void edge_agg4(const __half* __restrict__ h,
                                          const int2* __restrict__ edata,
                                          int e0, int e1, int lane, float4& acc) {
    const uint2* hq = (const uint2*)h;
    int e = e0;
    for (; e + 8 <= e1; e += 8) {
        int2 d0 = edata[e];
        int2 d1 = edata[e + 1];
        int2 d2 = edata[e + 2];
        int2 d3 = edata[e + 3];
        int2 d4 = edata[e + 4];
        int2 d5 = edata[e + 5];
        int2 d6 = edata[e + 6];
        int2 d7 = edata[e + 7];
        uint2 g0 = hq[d0.x * 4 + lane];
        uint2 g1 = hq[d1.x * 4 + lane];
        uint2 g2 = hq[d2.x * 4 + lane];
        uint2 g3 = hq[d3.x * 4 + lane];
        uint2 g4 = hq[d4.x * 4 + lane];
        uint2 g5 = hq[d5.x * 4 + lane];
        uint2 g6 = hq[d6.x * 4 + lane];
        uint2 g7 = hq[d7.x * 4 + lane];
        #define ACC4(d, g) { \
            float wv = __int_as_float((d).y); \
            __half2 a = *(__half2*)&(g).x; \
            __half2 b = *(__half2*)&(g).y; \
            float2 fa = __half22float2(a); \
            float2 fb = __half22float2(b); \
            acc.x += wv * fa.x; acc.y += wv * fa.y; \
            acc.z += wv * fb.x; acc.w += wv * fb.y; }
        ACC4(d0, g0) ACC4(d1, g1) ACC4(d2, g2) ACC4(d3, g3)
        ACC4(d4, g4) ACC4(d5, g5) ACC4(d6, g6) ACC4(d7, g7)
    }
    for (; e < e1; e++) {
        int2 d = edata[e];
        uint2 g = hq[d.x * 4 + lane];
        ACC4(d, g)
        #undef ACC4
    }
}

// conv1 aggregate (+b1, ReLU), fused h2 = x1 @ W2; hb = fp16(dinv * h2)
__global__ __launch_bounds__(256) void k_agg1(const __half* __restrict__ h1,
                                              const float* __restrict__ dinv,
                                              const int* __restrict__ offs,
                                              const int2* __restrict__ edata,
                                              const float* __restrict__ b1,
                                              const float* __restrict__ W2,
                                              __half* __restrict__ hb) {
    __shared__ float w2s[HID * HID];
    __shared__ float x1s[64 * 17];       // +1 pad: conflict-free column reads
    int tid = threadIdx.x;
    if (tid < HID * HID) w2s[tid] = W2[tid];
    int lane = tid & 3;
    int g = tid >> 2;
    int node = blockIdx.x * 64 + g;
    bool valid = node < N_NODES;
    int e0 = valid ? offs[node] : 0;
    int e1 = valid ? offs[node + 1] : 0;
    float4 acc = make_float4(0.f, 0.f, 0.f, 0.f);
    float d = 0.0f;
    if (valid) {
        uint2 sv = ((const uint2*)h1)[node * 4 + lane];
        __half2 s0 = *(__half2*)&sv.x;
        __half2 s1 = *(__half2*)&sv.y;
        float2 f0 = __half22float2(s0);
        float2 f1 = __half22float2(s1);
        acc = make_float4(f0.x, f0.y, f1.x, f1.y);
        d = dinv[node];
    }
    edge_agg4(h1, edata, e0, e1, lane, acc);
    if (valid) {
        float4 bb = *(const float4*)&b1[lane * 4];
        acc.x = fmaxf(d * acc.x + bb.x, 0.0f);
        acc.y = fmaxf(d * acc.y + bb.y, 0.0f);
        acc.z = fmaxf(d * acc.z + bb.z, 0.0f);
        acc.w = fmaxf(d * acc.w + bb.w, 0.0f);
        *(float4*)&x1s[g * 17 + lane * 4] = acc;
    }
    __syncthreads();
    if (valid) {
        float4 h2 = make_float4(0.f, 0.f, 0.f, 0.f);
        #pragma unroll
        for (int kk = 0; kk < HID; kk++) {
            float v = x1s[g * 17 + kk];
            float4 wv = *(const float4*)&w2s[kk * HID + lane * 4];
            h2.x += v * wv.x; h2.y += v * wv.y; h2.z += v * wv.z; h2.w += v * wv.w;
        }
        union { __half2 p[2]; uint2 u; } pk;
        pk.p[0] = __floats2half2_rn(d * h2.x, d * h2.y);
        pk.p[1] = __floats2half2_rn(d * h2.z, d * h2.w);
        ((uint2*)hb)[node * 4 + lane] = pk.u;
    }
}

// conv2 aggregate (+b2), classifier (16->40) + log_softmax
__global__ __launch_bounds__(256) void k_agg2(const __half* __restrict__ hb,
                                              const float* __restrict__ dinv,
                                              const int* __restrict__ offs,
                                              const int2* __restrict__ edata,
                                              const float* __restrict__ b2,
                                              const float* __restrict__ Wc,
                                              const float* __restrict__ bc,
                                              float* __restrict__ out) {
    __shared__ float wcs[HID * NCLS];    // 640 floats
    __shared__ float bcs[NCLS];
    __shared__ float x2s[64 * 17];
    int tid = threadIdx.x;
    for (int i = tid; i < HID * NCLS; i += 256) wcs[i] = Wc[i];
    if (tid < NCLS) bcs[tid] = bc[tid];
    int lane = tid & 3;
    int g = tid >> 2;
    int node = blockIdx.x * 64 + g;
    bool valid = node < N_NODES;
    int e0 = valid ? offs[node] : 0;
    int e1 = valid ? offs[node + 1] : 0;
    float4 acc = make_float4(0.f, 0.f, 0.f, 0.f);
    float d = 0.0f;
    if (valid) {
        uint2 sv = ((const uint2*)hb)[node * 4 + lane];
        __half2 s0 = *(__half2*)&sv.x;
        __half2 s1 = *(__half2*)&sv.y;
        float2 f0 = __half22float2(s0);
        float2 f1 = __half22float2(s1);
        acc = make_float4(f0.x, f0.y, f1.x, f1.y);
        d = dinv[node];
    }
    edge_agg4(hb, edata, e0, e1, lane, acc);
    if (valid) {
        float4 bb = *(const float4*)&b2[lane * 4];
        acc.x = d * acc.x + bb.x;
        acc.y = d * acc.y + bb.y;
        acc.z = d * acc.z + bb.z;
        acc.w = d * acc.w + bb.w;
        *(float4*)&x2s[g * 17 + lane * 4] = acc;
    }
    __syncthreads();
    if (valid) {
        float l[10];
        #pragma unroll
        for (int c = 0; c < 10; c++) l[c] = bcs[lane * 10 + c];
        #pragma unroll
        for (int kk = 0; kk < HID; kk++) {
            float v = x2s[g * 17 + kk];
            #pragma unroll
            for (int c = 0; c < 10; c++)
                l[c] += v * wcs[kk * NCLS + lane * 10 + c];
        }
        float m = l[0];
        #pragma unroll
        for (int c = 1; c < 10; c++) m = fmaxf(m, l[c]);
        m = fmaxf(m, __shfl_xor(m, 1, 64));
        m = fmaxf(m, __shfl_xor(m, 2, 64));
        float s = 0.0f;
        #pragma unroll
        for (int c = 0; c < 10; c++) s += expf(l[c] - m);
        s += __shfl_xor(s, 1, 64);
        s += __shfl_xor(s, 2, 64);
        float ls = logf(s) + m;
        #pragma unroll
        for (int c = 0; c < 10; c++)
            out[node * NCLS + lane * 10 + c] = l[c] - ls;
    }
}

// =================== tier-2: R5 atomic-CSR build ===================

__global__ __launch_bounds__(256) void k_init(int* cnt) {
    int i = blockIdx.x * 256 + threadIdx.x;
    if (i < N_NODES) cnt[i] = 0;
}

__global__ __launch_bounds__(256) void k_count(const int* col, int* cnt) {
    int e = blockIdx.x * 256 + threadIdx.x;
    atomicAdd(&cnt[col[e]], 1);
}

__global__ __launch_bounds__(1024) void k_scan1(const int* cnt, int* offs, int* bsum) {
    __shared__ int s[1024];
    int tid = threadIdx.x;
    int gid = blockIdx.x * 1024 + tid;
    int v = (gid < N_NODES) ? cnt[gid] : 0;
    s[tid] = v;
    __syncthreads();
    for (int o = 1; o < 1024; o <<= 1) {
        int t = (tid >= o) ? s[tid - o] : 0;
        __syncthreads();
        s[tid] += t;
        __syncthreads();
    }
    if (gid < N_NODES) offs[gid] = s[tid] - v;
    if (tid == 1023) bsum[blockIdx.x] = s[1023];
}

__global__ __launch_bounds__(128) void k_scan2(int* bsum) {
    __shared__ int s[128];
    int tid = threadIdx.x;
    int v = (tid < 98) ? bsum[tid] : 0;
    s[tid] = v;
    __syncthreads();
    for (int o = 1; o < 128; o <<= 1) {
        int t = (tid >= o) ? s[tid - o] : 0;
        __syncthreads();
        s[tid] += t;
        __syncthreads();
    }
    if (tid < 98) bsum[tid] = s[tid] - v;
}

__global__ __launch_bounds__(1024) void k_scan3(int* offs, int* cur, const int* bsum) {
    int tid = threadIdx.x;
    int gid = blockIdx.x * 1024 + tid;
    if (gid < N_NODES) {
        int o = offs[gid] + bsum[blockIdx.x];
        offs[gid] = o;
        cur[gid] = o;
    }
    if (gid == 0) offs[N_NODES] = N_EDGES;
}

__global__ __launch_bounds__(256) void k_scatter(const int* row, const int* col,
                                                 const float* w, int* cur, int2* edata) {
    int e = blockIdx.x * 256 + threadIdx.x;
    int r = row[e];
    int c = col[e];
    int p = atomicAdd(&cur[c], 1);
    edata[p] = make_int2(r, __float_as_int(w[e]));
}

__global__ __launch_bounds__(256) void k_deg_dinv(const int* offs, const int2* edata,
                                                  float* dinv) {
    int tid = threadIdx.x;
    int lane = tid & 15;
    int node = blockIdx.x * 16 + (tid >> 4);
    int e0 = offs[node], e1 = offs[node + 1];
    float s = 0.0f;
    for (int e = e0 + lane; e < e1; e += 16)
        s += __int_as_float(edata[e].y);
    for (int o = 1; o < 16; o <<= 1) s += __shfl_xor(s, o, 64);
    if (lane == 0) dinv[node] = 1.0f / sqrtf(1.0f + s);
}

// =================== tier-3: edge-atomic fallback ===================

__global__ __launch_bounds__(256) void k_init_deg(float* deg) {
    int i = blockIdx.x * 256 + threadIdx.x;
    if (i < N_NODES) deg[i] = 1.0f;
}

__global__ __launch_bounds__(256) void k_deg_only(const int* col, const float* w, float* deg) {
    int e = blockIdx.x * 256 + threadIdx.x;
    atomicAdd(&deg[col[e]], w[e]);
}

__global__ __launch_bounds__(256) void k_dinv(float* deg) {
    int i = blockIdx.x * 256 + threadIdx.x;
    if (i < N_NODES) {
        float d = deg[i];
        deg[i] = (d > 0.0f) ? 1.0f / sqrtf(d) : 0.0f;
    }
}

__global__ __launch_bounds__(256) void k_self(const float* dinv, const float* h, float* agg) {
    int i = blockIdx.x * 256 + threadIdx.x;
    float d = dinv[i >> 4];
    agg[i] = d * d * h[i];
}

__global__ __launch_bounds__(256) void k_edge_atomic(const int* row, const int* col,
                                                     const float* w, const float* dinv,
                                                     const float* h, float* agg) {
    int gid = blockIdx.x * 256 + threadIdx.x;
    int e = gid >> 4, lane = gid & 15;
    int r = row[e], c = col[e];
    float nrm = dinv[r] * w[e] * dinv[c];
    atomicAdd(&agg[c * HID + lane], nrm * h[r * HID + lane]);
}

__global__ __launch_bounds__(256) void k_bias_relu_gemm2(const float* agg, const float* b1,
                                                         const float* W2, float* out2) {
    __shared__ float w2s[HID * HID];
    int tid = threadIdx.x;
    if (tid < HID * HID) w2s[tid] = W2[tid];
    __syncthreads();
    int lane = tid & 15;
    int node = blockIdx.x * 16 + (tid >> 4);
    float acc = fmaxf(agg[node * HID + lane] + b1[lane], 0.0f);
    int base = tid & 48;
    float h2 = 0.0f;
    for (int k = 0; k < HID; k++) {
        float v = __shfl(acc, base + k, 64);
        h2 += v * w2s[k * HID + lane];
    }
    out2[node * HID + lane] = h2;
}

__global__ __launch_bounds__(256) void k_final(const float* agg, const float* b2,
                                               const float* Wc, const float* bc, float* out) {
    __shared__ float wcs[HID * NCLS];
    __shared__ float bcs[NCLS];
    int tid = threadIdx.x;
    for (int i = tid; i < HID * NCLS; i += 256) wcs[i] = Wc[i];
    if (tid < NCLS) bcs[tid] = bc[tid];
    __syncthreads();
    int lane = tid & 15;
    int node = blockIdx.x * 16 + (tid >> 4);
    float acc = agg[node * HID + lane] + b2[lane];
    float l0 = bcs[lane];
    float l1 = bcs[lane + 16];
    float l2 = (lane < 8) ? bcs[lane + 32] : 0.0f;
    int base = tid & 48;
    for (int k = 0; k < HID; k++) {
        float v = __shfl(acc, base + k, 64);
        l0 += v * wcs[k * NCLS + lane];
        l1 += v * wcs[k * NCLS + lane + 16];
        if (lane < 8) l2 += v * wcs[k * NCLS + lane + 32];
    }
    float m = fmaxf(l0, l1);
    if (lane < 8) m = fmaxf(m, l2);
    for (int o = 1; o < 16; o <<= 1) m = fmaxf(m, __shfl_xor(m, o, 64));
    float s = expf(l0 - m) + expf(l1 - m) + ((lane < 8) ? expf(l2 - m) : 0.0f);
    for (int o = 1; o < 16; o <<= 1) s += __shfl_xor(s, o, 64);
    float ls = logf(s) + m;
    out[node * NCLS + lane] = l0 - ls;
    out[node * NCLS + lane + 16] = l1 - ls;
    if (lane < 8) out[node * NCLS + lane + 32] = l2 - ls;
}

extern "C" void kernel_launch(void* const* d_in, const int* in_sizes, int n_in,
                              void* d_out, int out_size, void* d_ws, size_t ws_size,
                              hipStream_t stream) {
    const float* z     = (const float*)d_in[0];
    const int*   eidx  = (const int*)d_in[1];
    const float* eattr = (const float*)d_in[2];
    const float* W1    = (const float*)d_in[3];
    const float* b1    = (const float*)d_in[4];
    const float* W2    = (const float*)d_in[5];
    const float* b2    = (const float*)d_in[6];
    const float* Wc    = (const float*)d_in[7];
    const float* bc    = (const float*)d_in[8];
    float* out = (float*)d_out;

    char* ws = (char*)d_ws;
    const int* rowp = eidx;
    const int* colp = eidx + N_EDGES;

    int nblk = (N_NODES + 255) / 256;               // 391
    int eblk = N_EDGES / 256;                       // 25000
    int sblk = (N_NODES + 1023) / 1024;             // 98
    int gblk = (N_NODES + 63) / 64;                 // 1563
    int ablk = (N_NODES + 63) / 64;                 // 1563 (4-lane agg: 64 nodes/block)
    int a16  = N_NODES / 16;                        // 6250 (16-lane helpers)
    int fblk = (N_NODES * HID) / 256;               // 6250
    int exblk = (N_EDGES * HID) / 256;              // 400000

    if (ws_size >= (size_t)WS_T1_NEED) {
        // ---------- tier-1: atomic-free CSR build + fp16 gather tables ----------
        int*    cbase  = (int*)(ws + OFF_CB);
        int*    tot    = (int*)(ws + OFF_TOT);
        float*  dinv   = (float*)(ws + OFF_DINV);   // deg, then rsqrt in place
        int*    offs   = (int*)(ws + OFF_OFFS);
        int*    histc  = (int*)(ws + OFF_HIST);     // overlays edata (time-disjoint)
        int*    histex = (int*)(ws + OFF_HISTEX);
        int*    cnt    = (int*)(ws + OFF_CNT);      // overlays edata (time-disjoint)
        int2*   ebuf1  = (int2*)(ws + OFF_EBUF1);
        int2*   edat   = (int2*)(ws + OFF_EDATA);
        __half* h1     = (__half*)(ws + OFF_H1);
        __half* hb     = (__half*)(ws + OFF_HB);

        k_init2<<<nblk, 256, 0, stream>>>(cnt, dinv);            // cnt=0, deg=1
        k_hist<<<B_PART, 1024, 0, stream>>>(colp, histc);
        k_colscan<<<K_BKT, 1024, 0, stream>>>(histc, histex, tot);
        k_basescan<<<1, 1024, 0, stream>>>(tot, cbase);
        k_partition<<<B_PART, 1024, 0, stream>>>(rowp, colp, eattr, histc, histex,
                                                 cbase, ebuf1, cnt, dinv);
        k_bsOffs<<<K_BKT, BKT_NB, 0, stream>>>(cnt, cbase, offs, dinv);
        k_bsB<<<K_BKT, 1024, 0, stream>>>(ebuf1, cbase, offs, edat);
        k_gemm1<<<gblk, 256, 0, stream>>>(z, W1, h1, dinv);      // h1 overlays dead ebuf1
        k_agg1<<<ablk, 256, 0, stream>>>(h1, dinv, offs, edat, b1, W2, hb);
        k_agg2<<<ablk, 256, 0, stream>>>(hb, dinv, offs, edat, b2, Wc, bc, out);
    } else if (ws_size >= (size_t)WS_T2_NEED) {
        // ---------- tier-2: atomic-CSR path (R5) ----------
        float*  dinv = (float*)(ws + T2_DINV);
        int*    cnt  = (int*)(ws + T2_CNT);
        int*    offs = (int*)(ws + T2_OFFS);
        int2*   edat = (int2*)(ws + T2_EDATA);
        __half* h1   = (__half*)(ws + T2_H1);
        __half* hb   = (__half*)(ws + T2_HB);
        int*    bsum = (int*)(ws + T2_BSUM);

        k_init<<<nblk, 256, 0, stream>>>(cnt);
        k_count<<<eblk, 256, 0, stream>>>(colp, cnt);
        k_scan1<<<sblk, 1024, 0, stream>>>(cnt, offs, bsum);
        k_scan2<<<1, 128, 0, stream>>>(bsum);
        k_scan3<<<sblk, 1024, 0, stream>>>(offs, cnt, bsum);
        k_scatter<<<eblk, 256, 0, stream>>>(rowp, colp, eattr, cnt, edat);
        k_deg_dinv<<<a16, 256, 0, stream>>>(offs, edat, dinv);
        k_gemm1<<<gblk, 256, 0, stream>>>(z, W1, h1, dinv);
        k_agg1<<<ablk, 256, 0, stream>>>(h1, dinv, offs, edat, b1, W2, hb);
        k_agg2<<<ablk, 256, 0, stream>>>(hb, dinv, offs, edat, b2, Wc, bc, out);
    } else {
        // ---------- tier-3: edge-atomic fallback (f32 throughout) ----------
        float* deg = (float*)(ws + OFF3_DEG);
        float* h1  = (float*)(ws + OFF3_H1);
        float* hb  = (float*)(ws + OFF3_HB);

        k_init_deg<<<nblk, 256, 0, stream>>>(deg);
        k_deg_only<<<eblk, 256, 0, stream>>>(colp, eattr, deg);
        k_dinv<<<nblk, 256, 0, stream>>>(deg);
        k_gemm1f<<<gblk, 256, 0, stream>>>(z, W1, hb, nullptr);
        k_self<<<fblk, 256, 0, stream>>>(deg, hb, h1);
        k_edge_atomic<<<exblk, 256, 0, stream>>>(rowp, colp, eattr, deg, hb, h1);
        k_bias_relu_gemm2<<<a16, 256, 0, stream>>>(h1, b1, W2, hb);
        k_self<<<fblk, 256, 0, stream>>>(deg, hb, h1);
        k_edge_atomic<<<exblk, 256, 0, stream>>>(rowp, colp, eattr, deg, hb, h1);
        k_final<<<a16, 256, 0, stream>>>(h1, b2, Wc, bc, out);
    }
}

// Round 10
// 381.043 us; speedup vs baseline: 2.2973x; 2.2973x over previous
//
#include <hip/hip_runtime.h>
#include <hip/hip_bf16.h>
#include <hip/hip_fp16.h>

// GCN inference: conv1(128->16)+ReLU -> conv2(16->16) -> linear(16->40) -> log_softmax
// R17 post-mortem: FALSIFIER FIRED -- per-edge global cnt/deg atomics in
// partition produced 467MB HBM writes (cross-XCD coherence point serializes
// device-scope atomics; ~32B HBM traffic per op at 12.8M ops). PERMANENT
// LESSON: global atomics OK at ~100K ops, catastrophic at ~10M. Reverted to
// R16 (394.6us verified). R18: edata shrinks to 4B/edge -- post-sort records
// need only (row 17b, w). Weights are uniform[0,1) -> positive -> fp16 sign
// bit 0 -> w fits 15 bits: packed = row | (half_bits(w)<<17). Halves
// bucketsort writeout + both agg edata streams (-77MB); bucketsort LDS
// staging 73.7->36.9KB (occupancy 2->3-4 blocks/CU). ebuf1 keeps f32 w so
// deg/dinv stay exact; only aggregation weight is fp16-rounded (~5e-4 rel,
// same class as the verified fp16 feature tables).

#define N_NODES 100000
#define N_EDGES 6400000
#define IN_DIM  128
#define HID     16
#define NCLS    40

#define K_BKT    782         // buckets = col>>7, 128 nodes each (last: 32)
#define BKT_SH   7
#define BKT_NB   128         // nodes per bucket
#define BKT_MASK 127
#define B_PART   1000        // histogram/partition blocks
#define CHUNK    6400        // edges per partition block (fits LDS staging)
#define BS_CAP   9216        // bucketsort LDS staging capacity (edges)

// ---- tier-1 workspace layout (bytes) ----
#define OFF_CB    0          // int[783] bucket bases
#define OFF_TOT   4096       // int[782] bucket totals
#define OFF_DINV  8192       // float[N]
#define OFF_OFFS  408192     // int[N+1]
#define OFF_EBUF1 808256     // int2[E] bucket-major edges (dead after bucketsort)
#define OFF_EDATA 52008256   // uint[E] packed CSR (row | half_bits(w)<<17) -- 25.6MB
#define OFF_HIST   OFF_EDATA               // int[1000*782] (dead before bucketsort writes)
#define OFF_HISTEX (OFF_EDATA + 3128000)   // int[1000*782]
#define WS_T1_NEED 103600000
// h1/hb (fp16, 3.2MB each) overlay the dead ebuf1 region:
#define OFF_H1    OFF_EBUF1
#define OFF_HB    (OFF_EBUF1 + 3200000)

// ---- tier-2 workspace layout (R5 atomic-CSR path, fp16 h, packed edata) ----
#define T2_DINV  0
#define T2_CNT   400128
#define T2_OFFS  800256
#define T2_EDATA 1200384
#define T2_H1    52400384
#define T2_HB    58800384
#define T2_BSUM  65200384
#define WS_T2_NEED 65210000

// ---- tier-3 fallback layout ----
#define OFF3_DEG 0
#define OFF3_H1  400128
#define OFF3_HB  6800384

__device__ __forceinline__ unsigned int pack_edge(int row17, float w) {
    unsigned short hb = __half_as_ushort(__float2half_rn(w));   // sign bit 0 (w >= 0)
    return (unsigned int)row17 | ((unsigned int)(hb & 0x7FFF) << 17);
}

__device__ __forceinline__ float unpack_w(unsigned int p) {
    return __half2float(__ushort_as_half((unsigned short)(p >> 17)));
}

// =================== tier-1: deterministic CSR build ===================

__global__ __launch_bounds__(1024) void k_hist(const int* col, int* histcnt) {
    __shared__ int h[K_BKT];
    int t = threadIdx.x;
    if (t < K_BKT) h[t] = 0;
    __syncthreads();
    int b = blockIdx.x;
    const int4* c4 = (const int4*)(col + b * CHUNK);
    for (int i = t; i < CHUNK / 4; i += 1024) {
        int4 c = c4[i];
        atomicAdd(&h[c.x >> BKT_SH], 1);              // LDS int atomic: fast path
        atomicAdd(&h[c.y >> BKT_SH], 1);
        atomicAdd(&h[c.z >> BKT_SH], 1);
        atomicAdd(&h[c.w >> BKT_SH], 1);
    }
    __syncthreads();
    if (t < K_BKT) histcnt[b * K_BKT + t] = h[t];
}

// one block per bucket k: exclusive-scan histcnt[.][k] over the 1000 blocks
__global__ __launch_bounds__(1024) void k_colscan(const int* histcnt, int* histex, int* tot) {
    __shared__ int s[1024];
    int t = threadIdx.x;
    int k = blockIdx.x;
    int v = (t < B_PART) ? histcnt[t * K_BKT + k] : 0;
    s[t] = v;
    __syncthreads();
    for (int o = 1; o < 1024; o <<= 1) {
        int a = (t >= o) ? s[t - o] : 0;
        __syncthreads();
        s[t] += a;
        __syncthreads();
    }
    if (t < B_PART) histex[t * K_BKT + k] = s[t] - v;  // exclusive
    if (t == 0) tot[k] = s[B_PART - 1];                // inclusive total
}

__global__ __launch_bounds__(1024) void k_basescan(const int* tot, int* cbase) {
    __shared__ int s[1024];
    int t = threadIdx.x;
    int v = (t < K_BKT) ? tot[t] : 0;
    s[t] = v;
    __syncthreads();
    for (int o = 1; o < 1024; o <<= 1) {
        int a = (t >= o) ? s[t - o] : 0;
        __syncthreads();
        s[t] += a;
        __syncthreads();
    }
    if (t < K_BKT) cbase[t] = s[t] - v;               // exclusive
    if (t == 0) cbase[K_BKT] = N_EDGES;
}

// LDS-staged partition: counting-sort the block's chunk in LDS, then write
// bucket-segments to global in slot order (coalesced runs).
// packed = row | (col_local<<17)
__global__ __launch_bounds__(1024) void k_partition(const int* row, const int* col,
                                                    const float* w, const int* histcnt,
                                                    const int* histex, const int* cbase,
                                                    int2* ebuf1) {
    __shared__ int2 led[CHUNK];          // 51.2KB staged edges
    __shared__ int  sscan[1024];
    __shared__ int  lbase[K_BKT + 1];
    __shared__ int  gofs[K_BKT];
    __shared__ int  cur[K_BKT];
    int t = threadIdx.x;
    int b = blockIdx.x;
    int v = (t < K_BKT) ? histcnt[b * K_BKT + t] : 0;
    sscan[t] = v;
    __syncthreads();
    for (int o = 1; o < 1024; o <<= 1) {
        int a = (t >= o) ? sscan[t - o] : 0;
        __syncthreads();
        sscan[t] += a;
        __syncthreads();
    }
    if (t < K_BKT) {
        int ex = sscan[t] - v;
        lbase[t] = ex;
        cur[t] = ex;
        gofs[t] = cbase[t] + histex[b * K_BKT + t] - ex;
    }
    if (t == 0) lbase[K_BKT] = CHUNK;
    __syncthreads();
    int end = (b + 1) * CHUNK;
    int e = b * CHUNK + t;
    for (; e + 1024 < end; e += 2048) {
        int c0 = col[e],  c1 = col[e + 1024];
        int r0 = row[e],  r1 = row[e + 1024];
        float w0 = w[e],  w1 = w[e + 1024];
        int p0 = atomicAdd(&cur[c0 >> BKT_SH], 1);
        int p1 = atomicAdd(&cur[c1 >> BKT_SH], 1);
        led[p0] = make_int2(r0 | ((c0 & BKT_MASK) << 17), __float_as_int(w0));
        led[p1] = make_int2(r1 | ((c1 & BKT_MASK) << 17), __float_as_int(w1));
    }
    for (; e < end; e += 1024) {
        int c = col[e];
        int p = atomicAdd(&cur[c >> BKT_SH], 1);
        led[p] = make_int2(row[e] | ((c & BKT_MASK) << 17), __float_as_int(w[e]));
    }
    __syncthreads();
    for (int i = t; i < CHUNK; i += 1024) {
        int2 ed = led[i];
        int lo = 0, hi = K_BKT;
        while (hi - lo > 1) {
            int mid = (lo + hi) >> 1;
            if (lbase[mid] <= i) lo = mid; else hi = mid;
        }
        ebuf1[gofs[lo] + i] = ed;
    }
}

// per-bucket fine counting sort -> PACKED edata CSR (4B/edge); offs + dinv.
// Pass B scatters into LDS at LOCAL positions, then writes out coalesced.
__global__ __launch_bounds__(1024) void k_bucketsort(const int2* ebuf1, const int* cbase,
                                                     unsigned int* edata, int* offs,
                                                     float* dinv) {
    __shared__ unsigned int led[BS_CAP]; // 36.9KB packed staging
    __shared__ int   cnt[BKT_NB];
    __shared__ float degw[BKT_NB];
    __shared__ int   sc[BKT_NB];
    __shared__ int   cur[BKT_NB];
    int t = threadIdx.x;
    int k = blockIdx.x;
    if (t < BKT_NB) { cnt[t] = 0; degw[t] = 0.0f; }
    __syncthreads();
    int e0 = cbase[k], e1 = cbase[k + 1];
    // pass A: local histogram + weighted degree (f32-exact), 4x unrolled
    int e = e0 + t;
    for (; e + 3072 < e1; e += 4096) {
        int2 v0 = ebuf1[e];
        int2 v1 = ebuf1[e + 1024];
        int2 v2 = ebuf1[e + 2048];
        int2 v3 = ebuf1[e + 3072];
        int a0 = v0.x >> 17, a1 = v1.x >> 17, a2 = v2.x >> 17, a3 = v3.x >> 17;
        atomicAdd(&cnt[a0], 1); atomicAdd(&degw[a0], __int_as_float(v0.y));
        atomicAdd(&cnt[a1], 1); atomicAdd(&degw[a1], __int_as_float(v1.y));
        atomicAdd(&cnt[a2], 1); atomicAdd(&degw[a2], __int_as_float(v2.y));
        atomicAdd(&cnt[a3], 1); atomicAdd(&degw[a3], __int_as_float(v3.y));
    }
    for (; e < e1; e += 1024) {
        int2 v = ebuf1[e];
        int cl = v.x >> 17;
        atomicAdd(&cnt[cl], 1);
        atomicAdd(&degw[cl], __int_as_float(v.y));
    }
    __syncthreads();
    int c0 = (t < BKT_NB) ? cnt[t] : 0;
    if (t < BKT_NB) sc[t] = c0;
    __syncthreads();
    for (int o = 1; o < BKT_NB; o <<= 1) {
        int a = (t < BKT_NB && t >= o) ? sc[t - o] : 0;
        __syncthreads();
        if (t < BKT_NB) sc[t] += a;
        __syncthreads();
    }
    if (t < BKT_NB) {
        int ex = sc[t] - c0;
        cur[t] = ex;                                  // local position base
        int node = k * BKT_NB + t;
        if (node < N_NODES) {
            offs[node] = e0 + ex;
            dinv[node] = rsqrtf(1.0f + degw[t]);
        }
    }
    if (k == 0 && t == 0) offs[N_NODES] = N_EDGES;
    __syncthreads();
    int len = e1 - e0;
    if (len <= BS_CAP) {
        e = e0 + t;
        for (; e + 3072 < e1; e += 4096) {
            int2 v0 = ebuf1[e];
            int2 v1 = ebuf1[e + 1024];
            int2 v2 = ebuf1[e + 2048];
            int2 v3 = ebuf1[e + 3072];
            int p0 = atomicAdd(&cur[v0.x >> 17], 1);
            int p1 = atomicAdd(&cur[v1.x >> 17], 1);
            int p2 = atomicAdd(&cur[v2.x >> 17], 1);
            int p3 = atomicAdd(&cur[v3.x >> 17], 1);
            led[p0] = pack_edge(v0.x & 131071, __int_as_float(v0.y));
            led[p1] = pack_edge(v1.x & 131071, __int_as_float(v1.y));
            led[p2] = pack_edge(v2.x & 131071, __int_as_float(v2.y));
            led[p3] = pack_edge(v3.x & 131071, __int_as_float(v3.y));
        }
        for (; e < e1; e += 1024) {
            int2 v = ebuf1[e];
            int p = atomicAdd(&cur[v.x >> 17], 1);
            led[p] = pack_edge(v.x & 131071, __int_as_float(v.y));
        }
        __syncthreads();
        // coalesced linear writeout (4B/edge)
        for (int i = t; i < len; i += 1024)
            edata[e0 + i] = led[i];
    } else {
        // fallback (capacity exceeded; statistically never): direct scatter
        e = e0 + t;
        for (; e < e1; e += 1024) {
            int2 v = ebuf1[e];
            int p = atomicAdd(&cur[v.x >> 17], 1);
            edata[e0 + p] = pack_edge(v.x & 131071, __int_as_float(v.y));
        }
    }
}

// =================== shared compute kernels ===================

// h1 = fp16(dinv[node] * (z @ W1))
__global__ __launch_bounds__(256) void k_gemm1(const float* z, const float* W1,
                                               __half* h1, const float* dinv) {
    __shared__ float w1s[IN_DIM * HID];
    __shared__ float zs[64 * 132];
    int tid = threadIdx.x;
    for (int i = tid; i < IN_DIM * HID / 4; i += 256)
        ((float4*)w1s)[i] = ((const float4*)W1)[i];
    int nodeBase = blockIdx.x * 64;
    for (int i = tid; i < 64 * 32; i += 256) {
        int nl = i >> 5, kq = i & 31;
        int node = nodeBase + nl;
        float4 v = (node < N_NODES) ? ((const float4*)z)[node * 32 + kq]
                                    : make_float4(0.f, 0.f, 0.f, 0.f);
        *(float4*)&zs[nl * 132 + kq * 4] = v;
    }
    __syncthreads();
    int nl = tid >> 2;
    int jb = (tid & 3) * 4;
    int node = nodeBase + nl;
    float4 acc = make_float4(0.f, 0.f, 0.f, 0.f);
    for (int k = 0; k < IN_DIM; k++) {
        float s = zs[nl * 132 + k];
        float4 wv = *(const float4*)&w1s[k * HID + jb];
        acc.x += s * wv.x; acc.y += s * wv.y; acc.z += s * wv.z; acc.w += s * wv.w;
    }
    if (node < N_NODES) {
        float dv = dinv ? dinv[node] : 1.0f;
        union { __half2 h2[2]; uint2 u; } pk;
        pk.h2[0] = __floats2half2_rn(acc.x * dv, acc.y * dv);
        pk.h2[1] = __floats2half2_rn(acc.z * dv, acc.w * dv);
        ((uint2*)h1)[node * 4 + (tid & 3)] = pk.u;
    }
}

// f32-output variant for tier-3
__global__ __launch_bounds__(256) void k_gemm1f(const float* z, const float* W1, float* h1,
                                                const float* dinv) {
    __shared__ float w1s[IN_DIM * HID];
    __shared__ float zs[64 * 132];
    int tid = threadIdx.x;
    for (int i = tid; i < IN_DIM * HID / 4; i += 256)
        ((float4*)w1s)[i] = ((const float4*)W1)[i];
    int nodeBase = blockIdx.x * 64;
    for (int i = tid; i < 64 * 32; i += 256) {
        int nl = i >> 5, kq = i & 31;
        int node = nodeBase + nl;
        float4 v = (node < N_NODES) ? ((const float4*)z)[node * 32 + kq]
                                    : make_float4(0.f, 0.f, 0.f, 0.f);
        *(float4*)&zs[nl * 132 + kq * 4] = v;
    }
    __syncthreads();
    int nl = tid >> 2;
    int jb = (tid & 3) * 4;
    int node = nodeBase + nl;
    float4 acc = make_float4(0.f, 0.f, 0.f, 0.f);
    for (int k = 0; k < IN_DIM; k++) {
        float s = zs[nl * 132 + k];
        float4 wv = *(const float4*)&w1s[k * HID + jb];
        acc.x += s * wv.x; acc.y += s * wv.y; acc.z += s * wv.z; acc.w += s * wv.w;
    }
    if (node < N_NODES) {
        float dv = dinv ? dinv[node] : 1.0f;
        acc.x *= dv; acc.y *= dv; acc.z *= dv; acc.w *= dv;
        ((float4*)h1)[node * 4 + (tid & 3)] = acc;
    }
}

// 4-lane/node edge aggregation over PACKED 4B edges: each lane gathers
// uint2 = 4 fp16 features; 8-deep unroll (16 loads in flight/lane).
__device__ __forceinline__ void edge_agg4(const __half* __restrict__ h,
                                          const unsigned int* __restrict__ edata,
                                          int e0, int e1, int lane, float4& acc) {
    const uint2* hq = (const uint2*)h;
    int e = e0;
    for (; e + 8 <= e1; e += 8) {
        unsigned int d0 = edata[e];
        unsigned int d1 = edata[e + 1];
        unsigned int d2 = edata[e + 2];
        unsigned int d3 = edata[e + 3];
        unsigned int d4 = edata[e + 4];
        unsigned int d5 = edata[e + 5];
        unsigned int d6 = edata[e + 6];
        unsigned int d7 = edata[e + 7];
        uint2 g0 = hq[(d0 & 131071) * 4 + lane];
        uint2 g1 = hq[(d1 & 131071) * 4 + lane];
        uint2 g2 = hq[(d2 & 131071) * 4 + lane];
        uint2 g3 = hq[(d3 & 131071) * 4 + lane];
        uint2 g4 = hq[(d4 & 131071) * 4 + lane];
        uint2 g5 = hq[(d5 & 131071) * 4 + lane];
        uint2 g6 = hq[(d6 & 131071) * 4 + lane];
        uint2 g7 = hq[(d7 & 131071) * 4 + lane];
        #define ACC4(d, g) { \
            float wv = unpack_w(d); \
            __half2 a = *(__half2*)&(g).x; \
            __half2 b = *(__half2*)&(g).y; \
            float2 fa = __half22float2(a); \
            float2 fb = __half22float2(b); \
            acc.x += wv * fa.x; acc.y += wv * fa.y; \
            acc.z += wv * fb.x; acc.w += wv * fb.y; }
        ACC4(d0, g0) ACC4(d1, g1) ACC4(d2, g2) ACC4(d3, g3)
        ACC4(d4, g4) ACC4(d5, g5) ACC4(d6, g6) ACC4(d7, g7)
    }
    for (; e < e1; e++) {
        unsigned int d = edata[e];
        uint2 g = hq[(d & 131071) * 4 + lane];
        ACC4(d, g)
        #undef ACC4
    }
}

// conv1 aggregate (+b1, ReLU), fused h2 = x1 @ W2; hb = fp16(dinv * h2)
__global__ __launch_bounds__(256) void k_agg1(const __half* __restrict__ h1,
                                              const float* __restrict__ dinv,
                                              const int* __restrict__ offs,
                                              const unsigned int* __restrict__ edata,
                                              const float* __restrict__ b1,
                                              const float* __restrict__ W2,
                                              __half* __restrict__ hb) {
    __shared__ float w2s[HID * HID];
    __shared__ float x1s[64 * 17];       // +1 pad: conflict-free column reads
    int tid = threadIdx.x;
    if (tid < HID * HID) w2s[tid] = W2[tid];
    int lane = tid & 3;
    int g = tid >> 2;
    int node = blockIdx.x * 64 + g;
    bool valid = node < N_NODES;
    int e0 = valid ? offs[node] : 0;
    int e1 = valid ? offs[node + 1] : 0;
    float4 acc = make_float4(0.f, 0.f, 0.f, 0.f);
    float d = 0.0f;
    if (valid) {
        uint2 sv = ((const uint2*)h1)[node * 4 + lane];
        __half2 s0 = *(__half2*)&sv.x;
        __half2 s1 = *(__half2*)&sv.y;
        float2 f0 = __half22float2(s0);
        float2 f1 = __half22float2(s1);
        acc = make_float4(f0.x, f0.y, f1.x, f1.y);
        d = dinv[node];
    }
    edge_agg4(h1, edata, e0, e1, lane, acc);
    if (valid) {
        float4 bb = *(const float4*)&b1[lane * 4];
        acc.x = fmaxf(d * acc.x + bb.x, 0.0f);
        acc.y = fmaxf(d * acc.y + bb.y, 0.0f);
        acc.z = fmaxf(d * acc.z + bb.z, 0.0f);
        acc.w = fmaxf(d * acc.w + bb.w, 0.0f);
        *(float4*)&x1s[g * 17 + lane * 4] = acc;
    }
    __syncthreads();
    if (valid) {
        float4 h2 = make_float4(0.f, 0.f, 0.f, 0.f);
        #pragma unroll
        for (int kk = 0; kk < HID; kk++) {
            float v = x1s[g * 17 + kk];
            float4 wv = *(const float4*)&w2s[kk * HID + lane * 4];
            h2.x += v * wv.x; h2.y += v * wv.y; h2.z += v * wv.z; h2.w += v * wv.w;
        }
        union { __half2 p[2]; uint2 u; } pk;
        pk.p[0] = __floats2half2_rn(d * h2.x, d * h2.y);
        pk.p[1] = __floats2half2_rn(d * h2.z, d * h2.w);
        ((uint2*)hb)[node * 4 + lane] = pk.u;
    }
}

// conv2 aggregate (+b2), classifier (16->40) + log_softmax
__global__ __launch_bounds__(256) void k_agg2(const __half* __restrict__ hb,
                                              const float* __restrict__ dinv,
                                              const int* __restrict__ offs,
                                              const unsigned int* __restrict__ edata,
                                              const float* __restrict__ b2,
                                              const float* __restrict__ Wc,
                                              const float* __restrict__ bc,
                                              float* __restrict__ out) {
    __shared__ float wcs[HID * NCLS];    // 640 floats
    __shared__ float bcs[NCLS];
    __shared__ float x2s[64 * 17];
    int tid = threadIdx.x;
    for (int i = tid; i < HID * NCLS; i += 256) wcs[i] = Wc[i];
    if (tid < NCLS) bcs[tid] = bc[tid];
    int lane = tid & 3;
    int g = tid >> 2;
    int node = blockIdx.x * 64 + g;
    bool valid = node < N_NODES;
    int e0 = valid ? offs[node] : 0;
    int e1 = valid ? offs[node + 1] : 0;
    float4 acc = make_float4(0.f, 0.f, 0.f, 0.f);
    float d = 0.0f;
    if (valid) {
        uint2 sv = ((const uint2*)hb)[node * 4 + lane];
        __half2 s0 = *(__half2*)&sv.x;
        __half2 s1 = *(__half2*)&sv.y;
        float2 f0 = __half22float2(s0);
        float2 f1 = __half22float2(s1);
        acc = make_float4(f0.x, f0.y, f1.x, f1.y);
        d = dinv[node];
    }
    edge_agg4(hb, edata, e0, e1, lane, acc);
    if (valid) {
        float4 bb = *(const float4*)&b2[lane * 4];
        acc.x = d * acc.x + bb.x;
        acc.y = d * acc.y + bb.y;
        acc.z = d * acc.z + bb.z;
        acc.w = d * acc.w + bb.w;
        *(float4*)&x2s[g * 17 + lane * 4] = acc;
    }
    __syncthreads();
    if (valid) {
        float l[10];
        #pragma unroll
        for (int c = 0; c < 10; c++) l[c] = bcs[lane * 10 + c];
        #pragma unroll
        for (int kk = 0; kk < HID; kk++) {
            float v = x2s[g * 17 + kk];
            #pragma unroll
            for (int c = 0; c < 10; c++)
                l[c] += v * wcs[kk * NCLS + lane * 10 + c];
        }
        float m = l[0];
        #pragma unroll
        for (int c = 1; c < 10; c++) m = fmaxf(m, l[c]);
        m = fmaxf(m, __shfl_xor(m, 1, 64));
        m = fmaxf(m, __shfl_xor(m, 2, 64));
        float s = 0.0f;
        #pragma unroll
        for (int c = 0; c < 10; c++) s += expf(l[c] - m);
        s += __shfl_xor(s, 1, 64);
        s += __shfl_xor(s, 2, 64);
        float ls = logf(s) + m;
        #pragma unroll
        for (int c = 0; c < 10; c++)
            out[node * NCLS + lane * 10 + c] = l[c] - ls;
    }
}

// =================== tier-2: R5 atomic-CSR build (packed edata) ===================

__global__ __launch_bounds__(256) void k_init(int* cnt) {
    int i = blockIdx.x * 256 + threadIdx.x;
    if (i < N_NODES) cnt[i] = 0;
}

__global__ __launch_bounds__(256) void k_count(const int* col, int* cnt) {
    int e = blockIdx.x * 256 + threadIdx.x;
    atomicAdd(&cnt[col[e]], 1);
}

__global__ __launch_bounds__(1024) void k_scan1(const int* cnt, int* offs, int* bsum) {
    __shared__ int s[1024];
    int tid = threadIdx.x;
    int gid = blockIdx.x * 1024 + tid;
    int v = (gid < N_NODES) ? cnt[gid] : 0;
    s[tid] = v;
    __syncthreads();
    for (int o = 1; o < 1024; o <<= 1) {
        int t = (tid >= o) ? s[tid - o] : 0;
        __syncthreads();
        s[tid] += t;
        __syncthreads();
    }
    if (gid < N_NODES) offs[gid] = s[tid] - v;
    if (tid == 1023) bsum[blockIdx.x] = s[1023];
}

__global__ __launch_bounds__(128) void k_scan2(int* bsum) {
    __shared__ int s[128];
    int tid = threadIdx.x;
    int v = (tid < 98) ? bsum[tid] : 0;
    s[tid] = v;
    __syncthreads();
    for (int o = 1; o < 128; o <<= 1) {
        int t = (tid >= o) ? s[tid - o] : 0;
        __syncthreads();
        s[tid] += t;
        __syncthreads();
    }
    if (tid < 98) bsum[tid] = s[tid] - v;
}

__global__ __launch_bounds__(1024) void k_scan3(int* offs, int* cur, const int* bsum) {
    int tid = threadIdx.x;
    int gid = blockIdx.x * 1024 + tid;
    if (gid < N_NODES) {
        int o = offs[gid] + bsum[blockIdx.x];
        offs[gid] = o;
        cur[gid] = o;
    }
    if (gid == 0) offs[N_NODES] = N_EDGES;
}

__global__ __launch_bounds__(256) void k_scatter(const int* row, const int* col,
                                                 const float* w, int* cur,
                                                 unsigned int* edata) {
    int e = blockIdx.x * 256 + threadIdx.x;
    int r = row[e];
    int c = col[e];
    int p = atomicAdd(&cur[c], 1);
    edata[p] = pack_edge(r, w[e]);
}

__global__ __launch_bounds__(256) void k_deg_dinv(const int* offs,
                                                  const unsigned int* edata,
                                                  float* dinv) {
    int tid = threadIdx.x;
    int lane = tid & 15;
    int node = blockIdx.x * 16 + (tid >> 4);
    int e0 = offs[node], e1 = offs[node + 1];
    float s = 0.0f;
    for (int e = e0 + lane; e < e1; e += 16)
        s += unpack_w(edata[e]);
    for (int o = 1; o < 16; o <<= 1) s += __shfl_xor(s, o, 64);
    if (lane == 0) dinv[node] = 1.0f / sqrtf(1.0f + s);
}

// =================== tier-3: edge-atomic fallback ===================

__global__ __launch_bounds__(256) void k_init_deg(float* deg) {
    int i = blockIdx.x * 256 + threadIdx.x;
    if (i < N_NODES) deg[i] = 1.0f;
}

__global__ __launch_bounds__(256) void k_deg_only(const int* col, const float* w, float* deg) {
    int e = blockIdx.x * 256 + threadIdx.x;
    atomicAdd(&deg[col[e]], w[e]);
}

__global__ __launch_bounds__(256) void k_dinv(float* deg) {
    int i = blockIdx.x * 256 + threadIdx.x;
    if (i < N_NODES) {
        float d = deg[i];
        deg[i] = (d > 0.0f) ? 1.0f / sqrtf(d) : 0.0f;
    }
}

__global__ __launch_bounds__(256) void k_self(const float* dinv, const float* h, float* agg) {
    int i = blockIdx.x * 256 + threadIdx.x;
    float d = dinv[i >> 4];
    agg[i] = d * d * h[i];
}

__global__ __launch_bounds__(256) void k_edge_atomic(const int* row, const int* col,
                                                     const float* w, const float* dinv,
                                                     const float* h, float* agg) {
    int gid = blockIdx.x * 256 + threadIdx.x;
    int e = gid >> 4, lane = gid & 15;
    int r = row[e], c = col[e];
    float nrm = dinv[r] * w[e] * dinv[c];
    atomicAdd(&agg[c * HID + lane], nrm * h[r * HID + lane]);
}

__global__ __launch_bounds__(256) void k_bias_relu_gemm2(const float* agg, const float* b1,
                                                         const float* W2, float* out2) {
    __shared__ float w2s[HID * HID];
    int tid = threadIdx.x;
    if (tid < HID * HID) w2s[tid] = W2[tid];
    __syncthreads();
    int lane = tid & 15;
    int node = blockIdx.x * 16 + (tid >> 4);
    float acc = fmaxf(agg[node * HID + lane] + b1[lane], 0.0f);
    int base = tid & 48;
    float h2 = 0.0f;
    for (int k = 0; k < HID; k++) {
        float v = __shfl(acc, base + k, 64);
        h2 += v * w2s[k * HID + lane];
    }
    out2[node * HID + lane] = h2;
}

__global__ __launch_bounds__(256) void k_final(const float* agg, const float* b2,
                                               const float* Wc, const float* bc, float* out) {
    __shared__ float wcs[HID * NCLS];
    __shared__ float bcs[NCLS];
    int tid = threadIdx.x;
    for (int i = tid; i < HID * NCLS; i += 256) wcs[i] = Wc[i];
    if (tid < NCLS) bcs[tid] = bc[tid];
    __syncthreads();
    int lane = tid & 15;
    int node = blockIdx.x * 16 + (tid >> 4);
    float acc = agg[node * HID + lane] + b2[lane];
    float l0 = bcs[lane];
    float l1 = bcs[lane + 16];
    float l2 = (lane < 8) ? bcs[lane + 32] : 0.0f;
    int base = tid & 48;
    for (int k = 0; k < HID; k++) {
        float v = __shfl(acc, base + k, 64);
        l0 += v * wcs[k * NCLS + lane];
        l1 += v * wcs[k * NCLS + lane + 16];
        if (lane < 8) l2 += v * wcs[k * NCLS + lane + 32];
    }
    float m = fmaxf(l0, l1);
    if (lane < 8) m = fmaxf(m, l2);
    for (int o = 1; o < 16; o <<= 1) m = fmaxf(m, __shfl_xor(m, o, 64));
    float s = expf(l0 - m) + expf(l1 - m) + ((lane < 8) ? expf(l2 - m) : 0.0f);
    for (int o = 1; o < 16; o <<= 1) s += __shfl_xor(s, o, 64);
    float ls = logf(s) + m;
    out[node * NCLS + lane] = l0 - ls;
    out[node * NCLS + lane + 16] = l1 - ls;
    if (lane < 8) out[node * NCLS + lane + 32] = l2 - ls;
}

extern "C" void kernel_launch(void* const* d_in, const int* in_sizes, int n_in,
                              void* d_out, int out_size, void* d_ws, size_t ws_size,
                              hipStream_t stream) {
    const float* z     = (const float*)d_in[0];
    const int*   eidx  = (const int*)d_in[1];
    const float* eattr = (const float*)d_in[2];
    const float* W1    = (const float*)d_in[3];
    const float* b1    = (const float*)d_in[4];
    const float* W2    = (const float*)d_in[5];
    const float* b2    = (const float*)d_in[6];
    const float* Wc    = (const float*)d_in[7];
    const float* bc    = (const float*)d_in[8];
    float* out = (float*)d_out;

    char* ws = (char*)d_ws;
    const int* rowp = eidx;
    const int* colp = eidx + N_EDGES;

    int nblk = (N_NODES + 255) / 256;               // 391
    int eblk = N_EDGES / 256;                       // 25000
    int sblk = (N_NODES + 1023) / 1024;             // 98
    int gblk = (N_NODES + 63) / 64;                 // 1563
    int ablk = (N_NODES + 63) / 64;                 // 1563 (4-lane agg: 64 nodes/block)
    int a16  = N_NODES / 16;                        // 6250 (16-lane helpers)
    int fblk = (N_NODES * HID) / 256;               // 6250
    int exblk = (N_EDGES * HID) / 256;              // 400000

    if (ws_size >= (size_t)WS_T1_NEED) {
        // ---------- tier-1: atomic-free CSR build + packed edata ----------
        int*          cbase  = (int*)(ws + OFF_CB);
        int*          tot    = (int*)(ws + OFF_TOT);
        float*        dinv   = (float*)(ws + OFF_DINV);
        int*          offs   = (int*)(ws + OFF_OFFS);
        int*          histc  = (int*)(ws + OFF_HIST);   // overlays edata (time-disjoint)
        int*          histex = (int*)(ws + OFF_HISTEX);
        int2*         ebuf1  = (int2*)(ws + OFF_EBUF1);
        unsigned int* edat   = (unsigned int*)(ws + OFF_EDATA);
        __half*       h1     = (__half*)(ws + OFF_H1);
        __half*       hb     = (__half*)(ws + OFF_HB);

        k_hist<<<B_PART, 1024, 0, stream>>>(colp, histc);
        k_colscan<<<K_BKT, 1024, 0, stream>>>(histc, histex, tot);
        k_basescan<<<1, 1024, 0, stream>>>(tot, cbase);
        k_partition<<<B_PART, 1024, 0, stream>>>(rowp, colp, eattr, histc, histex, cbase, ebuf1);
        k_bucketsort<<<K_BKT, 1024, 0, stream>>>(ebuf1, cbase, edat, offs, dinv);
        k_gemm1<<<gblk, 256, 0, stream>>>(z, W1, h1, dinv);      // h1 overlays dead ebuf1
        k_agg1<<<ablk, 256, 0, stream>>>(h1, dinv, offs, edat, b1, W2, hb);
        k_agg2<<<ablk, 256, 0, stream>>>(hb, dinv, offs, edat, b2, Wc, bc, out);
    } else if (ws_size >= (size_t)WS_T2_NEED) {
        // ---------- tier-2: atomic-CSR path (R5, packed edata) ----------
        float*        dinv = (float*)(ws + T2_DINV);
        int*          cnt  = (int*)(ws + T2_CNT);
        int*          offs = (int*)(ws + T2_OFFS);
        unsigned int* edat = (unsigned int*)(ws + T2_EDATA);
        __half*       h1   = (__half*)(ws + T2_H1);
        __half*       hb   = (__half*)(ws + T2_HB);
        int*          bsum = (int*)(ws + T2_BSUM);

        k_init<<<nblk, 256, 0, stream>>>(cnt);
        k_count<<<eblk, 256, 0, stream>>>(colp, cnt);
        k_scan1<<<sblk, 1024, 0, stream>>>(cnt, offs, bsum);
        k_scan2<<<1, 128, 0, stream>>>(bsum);
        k_scan3<<<sblk, 1024, 0, stream>>>(offs, cnt, bsum);
        k_scatter<<<eblk, 256, 0, stream>>>(rowp, colp, eattr, cnt, edat);
        k_deg_dinv<<<a16, 256, 0, stream>>>(offs, edat, dinv);
        k_gemm1<<<gblk, 256, 0, stream>>>(z, W1, h1, dinv);
        k_agg1<<<ablk, 256, 0, stream>>>(h1, dinv, offs, edat, b1, W2, hb);
        k_agg2<<<ablk, 256, 0, stream>>>(hb, dinv, offs, edat, b2, Wc, bc, out);
    } else {
        // ---------- tier-3: edge-atomic fallback (f32 throughout) ----------
        float* deg = (float*)(ws + OFF3_DEG);
        float* h1  = (float*)(ws + OFF3_H1);
        float* hb  = (float*)(ws + OFF3_HB);

        k_init_deg<<<nblk, 256, 0, stream>>>(deg);
        k_deg_only<<<eblk, 256, 0, stream>>>(colp, eattr, deg);
        k_dinv<<<nblk, 256, 0, stream>>>(deg);
        k_gemm1f<<<gblk, 256, 0, stream>>>(z, W1, hb, nullptr);
        k_self<<<fblk, 256, 0, stream>>>(deg, hb, h1);
        k_edge_atomic<<<exblk, 256, 0, stream>>>(rowp, colp, eattr, deg, hb, h1);
        k_bias_relu_gemm2<<<a16, 256, 0, stream>>>(h1, b1, W2, hb);
        k_self<<<fblk, 256, 0, stream>>>(deg, hb, h1);
        k_edge_atomic<<<exblk, 256, 0, stream>>>(rowp, colp, eattr, deg, hb, h1);
        k_final<<<a16, 256, 0, stream>>>(h1, b2, Wc, bc, out);
    }
}